// Round 11
// baseline (667.392 us; speedup 1.0000x reference)
//
#include <hip/hip_runtime.h>
#include <math.h>

#define TT 10
#define BB 32
#define CIN 3
#define COUT 64
#define HH 64
#define WW 64
#define HW (HH*WW)           // 4096
#define DECAY 0.2f
#define INH 1.625f
#define RS 68                // LDS row stride (floats): 272B, 16B-aligned
#define ISLAB ((size_t)HW * COUT)   // elems per (t,b) i-slab: 262144

__device__ __forceinline__ unsigned int enc_f(float f) {
    unsigned int u = __float_as_uint(f);
    return (u & 0x80000000u) ? ~u : (u | 0x80000000u);
}
__device__ __forceinline__ float dec_f(unsigned int u) {
    u = (u & 0x80000000u) ? (u & 0x7FFFFFFFu) : ~u;
    return __uint_as_float(u);
}

// Stage NROWS rows of x into LDS rows of stride RS (slot cl = x col cl-1,
// cl==0 / cl>=65 zero pad). Row r -> (ci = r/RPC, gh = ghbase + r%RPC - 1).
template <int NROWS, int RPC>
__device__ __forceinline__ void stage_x(float* sxf, const float* xb,
                                        int ghbase, int tid) {
    const int NSLOT = NROWS * RS;
    const int NITER = (NSLOT + 255) / 256;
    float vals[NITER];
    #pragma unroll
    for (int it = 0; it < NITER; it++) {
        int l = tid + it * 256;
        float v = 0.f;
        if (l < NSLOT) {
            int row = l / RS, cl = l % RS;
            int ci = row / RPC, rr = row % RPC;
            int gh = ghbase + rr - 1;
            if (cl >= 1 && cl <= 64 && gh >= 0 && gh < HH)
                v = xb[ci * HW + gh * WW + (cl - 1)];
        }
        vals[it] = v;
    }
    #pragma unroll
    for (int it = 0; it < NITER; it++) {
        int l = tid + it * 256;
        if (l < NSLOT) sxf[l] = vals[it];
    }
}

// Conv core (r10-proven): 16 px starting at p0 (16-aligned), lane = channel.
// Per (ci,kh) row: 18 floats via 4xb128+b64 wave-uniform broadcast; 48 FMA
// over 16 independent accs. fmaf order per px: k = ci*9+kh*3+kw ascending.
__device__ __forceinline__ void conv16(const float* __restrict__ sxbase,
                                       const int* rows, const float* w,
                                       int p0, float acc[16]) {
    #pragma unroll
    for (int j = 0; j < 16; j++) acc[j] = 0.f;
    #pragma unroll
    for (int q = 0; q < 9; q++) {            // q = ci*3 + kh
        const float* rp = sxbase + rows[q] * RS + p0;   // 16B-aligned
        float xr[18];
        float4 a0 = *(const float4*)(rp + 0);
        float4 a1 = *(const float4*)(rp + 4);
        float4 a2 = *(const float4*)(rp + 8);
        float4 a3 = *(const float4*)(rp + 12);
        float2 a4 = *(const float2*)(rp + 16);
        xr[0]=a0.x; xr[1]=a0.y; xr[2]=a0.z; xr[3]=a0.w;
        xr[4]=a1.x; xr[5]=a1.y; xr[6]=a1.z; xr[7]=a1.w;
        xr[8]=a2.x; xr[9]=a2.y; xr[10]=a2.z; xr[11]=a2.w;
        xr[12]=a3.x; xr[13]=a3.y; xr[14]=a3.z; xr[15]=a3.w;
        xr[16]=a4.x; xr[17]=a4.y;
        const float w0 = w[q * 3 + 0];
        const float w1 = w[q * 3 + 1];
        const float w2 = w[q * 3 + 2];
        #pragma unroll
        for (int j = 0; j < 16; j++) {
            acc[j] = fmaf(w0, xr[j],     acc[j]);
            acc[j] = fmaf(w1, xr[j + 1], acc[j]);
            acc[j] = fmaf(w2, xr[j + 2], acc[j]);
        }
    }
}

// ---------------------------------------------------------------------------
// Pass 1: conv ONCE, t-parallel. Writes i[t][b][h][w][c] (lane=c, coalesced
// 256B/px) + fused per-channel atomicMax threshold (per-lane max — lane IS
// the channel, so no shuffles, just a 4-entry LDS combine).
// Grid (16 rowgroups, B, nt) x 256 (wave = one row).
// ---------------------------------------------------------------------------
__global__ __launch_bounds__(256) void conv_kernel(
    const float* __restrict__ x,        // (T,B,3,64,64)
    const float* __restrict__ Wt,       // (64,3,3,3)
    float* __restrict__ ibuf,           // [nt][B][H][W][C]
    unsigned int* __restrict__ thr_raw, // (T,64) pre-zeroed
    int t0)
{
    __shared__ float sx[CIN * 6][RS];   // 6 rows per ci: h0-1 .. h0+4
    __shared__ float wmax[4][COUT];

    const int tid  = threadIdx.x;
    const int lane = tid & 63;          // channel
    const int wave = tid >> 6;          // row within 4-row group
    const int h0   = blockIdx.x * 4;
    const int b    = blockIdx.y;
    const int t    = t0 + blockIdx.z;

    float w[27];
    #pragma unroll
    for (int k = 0; k < 27; k++) w[k] = Wt[lane * 27 + k];

    const float* xb = x + ((size_t)t * BB + b) * (CIN * HW);
    stage_x<CIN * 6, 6>(&sx[0][0], xb, h0, tid);
    __syncthreads();

    int rows[9];
    #pragma unroll
    for (int ci = 0; ci < CIN; ci++)
        #pragma unroll
        for (int kh = 0; kh < 3; kh++)
            rows[ci * 3 + kh] = ci * 6 + wave + kh;

    float* ist = ibuf + ((size_t)blockIdx.z * BB + b) * ISLAB
                      + (size_t)(h0 + wave) * WW * COUT;

    float mx = -INFINITY;
    #pragma unroll 1
    for (int cc = 0; cc < 4; cc++) {
        float acc[16];
        conv16(&sx[0][0], rows, w, cc * 16, acc);
        #pragma unroll
        for (int j = 0; j < 16; j++) {
            ist[(size_t)(cc * 16 + j) * COUT + lane] = acc[j];  // coalesced
            mx = fmaxf(mx, acc[j]);
        }
    }

    wmax[wave][lane] = mx;
    __syncthreads();
    if (wave == 0) {
        float m = fmaxf(fmaxf(wmax[0][lane], wmax[1][lane]),
                        fmaxf(wmax[2][lane], wmax[3][lane]));
        atomicMax(&thr_raw[t * COUT + lane], enc_f(m));
    }
}

// ---------------------------------------------------------------------------
// Pass 2: pure streaming LIF — ZERO LDS, ZERO barriers.
// lane = channel, wave = 16 px of one (b,h) row; mem[16] in registers across
// all t. Coalesced i reads; ballot-gated wave WTA (bit-identical); fmask ->
// 4x float4 wave-local stores (each lane writes its full 64B line).
// Grid = B*H = 2048 blocks x 256.
// ---------------------------------------------------------------------------
__global__ __launch_bounds__(256) void lif_stream(
    const float* __restrict__ ibuf,           // [nt][B][H][W][C]
    const unsigned int* __restrict__ thr_raw, // (T,64)
    float* __restrict__ out,                  // (T,B,64,64,64)
    float* __restrict__ memws,                // [B][H][W][C] (slow path)
    int t0, int nt)
{
    const int tid  = threadIdx.x;
    const int lane = tid & 63;                // channel
    const int wave = tid >> 6;
    const int p0   = __builtin_amdgcn_readfirstlane(wave * 16);
    const int b    = blockIdx.x >> 6;
    const int h    = blockIdx.x & 63;

    float* mrow = memws + ((size_t)b * HH + h) * WW * COUT;

    float mem[16];
    if (t0 == 0) {
        #pragma unroll
        for (int j = 0; j < 16; j++) mem[j] = 0.f;
    } else {
        #pragma unroll
        for (int j = 0; j < 16; j++)
            mem[j] = mrow[(size_t)(p0 + j) * COUT + lane];  // coalesced
    }

    #pragma unroll 1
    for (int tt = 0; tt < nt; tt++) {
        const int t = t0 + tt;
        const float* ild = ibuf + ((size_t)tt * BB + b) * ISLAB
                                + (size_t)h * WW * COUT;

        float thr   = dec_f(thr_raw[t * COUT + lane]) + 1e-4f;
        float sinv  = 8.0f / thr;
        float s04   = 0.4f * thr;
        float sinh_ = INH * thr;

        int fmask = 0;
        #pragma unroll
        for (int j = 0; j < 16; j++) {
            float iv  = ild[(size_t)(p0 + j) * COUT + lane];  // coalesced
            float cur = fmaxf(iv, 0.f);
            float z   = (cur - s04) * sinv;
            float sig = 1.0f / (1.0f + expf(-z));
            float m   = mem[j] * DECAY + thr * sig;
            int   sp  = m > thr;
            float score = sp ? m : 0.f;

            unsigned long long blt = __ballot(sp);
            int fr = 0, sp_any = 0;
            if (blt) {   // wave-uniform, rare
                float bs = score;
                int   bc = lane;
                #pragma unroll
                for (int off = 32; off > 0; off >>= 1) {
                    float so = __shfl_xor(bs, off, 64);
                    int   co = __shfl_xor(bc, off, 64);
                    if (so > bs || (so == bs && co < bc)) { bs = so; bc = co; }
                }
                sp_any = __shfl(sp, bc, 64);   // winner's spike = any_sp
                fr     = (lane == bc) && sp;
            }
            mem[j] = fr ? 0.f : (m - (sp_any ? sinh_ : 0.f));
            if (fr) fmask |= (1 << j);
        }

        // wave-local stores: lane's channel row, its 16 px, 4x dwordx4
        float* ob = out + (((size_t)t * BB + b) * COUT + lane) * HW
                        + h * WW + p0;
        #pragma unroll
        for (int g = 0; g < 4; g++) {
            float4 v;
            v.x = (fmask >> (g * 4 + 0)) & 1 ? 1.f : 0.f;
            v.y = (fmask >> (g * 4 + 1)) & 1 ? 1.f : 0.f;
            v.z = (fmask >> (g * 4 + 2)) & 1 ? 1.f : 0.f;
            v.w = (fmask >> (g * 4 + 3)) & 1 ? 1.f : 0.f;
            *(float4*)(ob + g * 4) = v;
        }
    }

    if (t0 + nt < TT) {   // slow path: persist membrane
        #pragma unroll
        for (int j = 0; j < 16; j++)
            mrow[(size_t)(p0 + j) * COUT + lane] = mem[j];
    }
}

// ---------------------------------------------------------------------------
extern "C" void kernel_launch(void* const* d_in, const int* in_sizes, int n_in,
                              void* d_out, int out_size, void* d_ws, size_t ws_size,
                              hipStream_t stream) {
    const float* x = (const float*)d_in[0];   // (T,B,3,64,64)
    const float* W = (const float*)d_in[1];   // (64,3,3,3)
    float* out     = (float*)d_out;           // (T,B,64,64,64)

    char* ws = (char*)d_ws;
    unsigned int* thr = (unsigned int*)ws;                // (T,64)
    const size_t IOFF  = 65536;
    const size_t SLABB = ISLAB * sizeof(float);           // 33.55 MB per t

    hipMemsetAsync(thr, 0, TT * COUT * sizeof(unsigned int), stream);

    if (ws_size >= IOFF + TT * SLABB) {
        // fast path: all t at once; mem never leaves registers
        float* ibuf = (float*)(ws + IOFF);
        conv_kernel<<<dim3(HH / 4, BB, TT), 256, 0, stream>>>(x, W, ibuf, thr, 0);
        lif_stream<<<dim3(BB * HH), 256, 0, stream>>>(ibuf, thr, out,
                                                      (float*)(ws + IOFF), 0, TT);
    } else {
        // slow path: per-t ping-pong; membrane persists in ws
        float* ibuf  = (float*)(ws + IOFF);
        float* memws = (float*)(ws + IOFF + SLABB);
        for (int t = 0; t < TT; t++) {
            conv_kernel<<<dim3(HH / 4, BB, 1), 256, 0, stream>>>(x, W, ibuf, thr, t);
            lif_stream<<<dim3(BB * HH), 256, 0, stream>>>(ibuf, thr, out,
                                                          memws, t, 1);
        }
    }
}